// Round 9
// baseline (784.685 us; speedup 1.0000x reference)
//
#include <hip/hip_runtime.h>
#include <stdint.h>

#define B_ 4
#define T_ 500
#define L_ 120000
#define NH_ 100
// RWR(16) level sizes
#define N1_ 7500     // 120000/16
#define N2_ 469      // ceil(7500/16)
#define N2P_ 7504    // 469*16
#define N3_ 30       // ceil(469/16)
#define N3P_ 480     // 30*16
#define N4_ 2        // ceil(30/16)
#define N4P_ 32      // 2*16

#define ACT_NONE 0
#define ACT_LRELU 1
#define ACT_SOFTPLUS 2
#define ACT_SIGMOID 3

// ---------------- Threefry2x32-20 (partitionable; verified by elimination R1-R8) ----------------
__host__ __device__ __forceinline__ uint32_t tf_rotl(uint32_t v, int d) {
  return (v << d) | (v >> (32 - d));
}
__host__ __device__ __forceinline__ void tf_block(uint32_t k0, uint32_t k1,
                                                  uint32_t& x0, uint32_t& x1) {
  uint32_t k2 = k0 ^ k1 ^ 0x1BD11BDAu;
  x0 += k0; x1 += k1;
#define TF_R(d) x0 += x1; x1 = tf_rotl(x1, (d)); x1 ^= x0;
  TF_R(13) TF_R(15) TF_R(26) TF_R(6)   x0 += k1; x1 += k2 + 1u;
  TF_R(17) TF_R(29) TF_R(16) TF_R(24)  x0 += k2; x1 += k0 + 2u;
  TF_R(13) TF_R(15) TF_R(26) TF_R(6)   x0 += k0; x1 += k1 + 3u;
  TF_R(17) TF_R(29) TF_R(16) TF_R(24)  x0 += k1; x1 += k2 + 4u;
  TF_R(13) TF_R(15) TF_R(26) TF_R(6)   x0 += k2; x1 += k0 + 5u;
#undef TF_R
}

__device__ __forceinline__ float erfinv_xla(float x) {
  float w = -log1pf(-(x * x));
  float p;
  if (w < 5.0f) {
    w = w - 2.5f;
    p = 2.81022636e-08f;
    p = fmaf(p, w, 3.43273939e-07f);
    p = fmaf(p, w, -3.5233877e-06f);
    p = fmaf(p, w, -4.39150654e-06f);
    p = fmaf(p, w, 0.00021858087f);
    p = fmaf(p, w, -0.00125372503f);
    p = fmaf(p, w, -0.00417768164f);
    p = fmaf(p, w, 0.246640727f);
    p = fmaf(p, w, 1.50140941f);
  } else {
    w = sqrtf(w) - 3.0f;
    p = -0.000200214257f;
    p = fmaf(p, w, 0.000100950558f);
    p = fmaf(p, w, 0.00134934322f);
    p = fmaf(p, w, -0.00367342844f);
    p = fmaf(p, w, 0.00573950773f);
    p = fmaf(p, w, -0.0076224613f);
    p = fmaf(p, w, 0.00943887047f);
    p = fmaf(p, w, 1.00167406f);
    p = fmaf(p, w, 2.83297682f);
  }
  return p * x;
}

__device__ __forceinline__ float jax_normal(uint32_t k0, uint32_t k1, uint32_t e) {
  uint32_t x0 = 0u, x1 = e;
  tf_block(k0, k1, x0, x1);
  uint32_t bits = x0 ^ x1;
  float u = __uint_as_float((bits >> 9) | 0x3f800000u) - 1.0f;
  float v = __fadd_rn(__fmul_rn(u, 2.0f), -0x1.fffffep-1f);
  v = fmaxf(v, -0x1.fffffep-1f);
  return __fmul_rn((float)1.4142135623730951, erfinv_xla(v));
}

// accurate sin of an EXACT f32 argument: f64 Cody-Waite reduction
__device__ __forceinline__ float sin_acc(float xf) {
  double x = (double)xf;
  double kd = rint(x * 6.3661977236758138e-01);
  double r = fma(-kd, 1.5707963267948966e+00, x);
  r = fma(-kd, 6.1232339957367660e-17, r);
  float rf = (float)r;
  float y = rf * rf;
  float ps = fmaf(y, 2.7557319e-06f, -1.9841270e-04f);
  ps = fmaf(y, ps, 8.3333335e-03f);
  ps = fmaf(y, ps, -0.16666667f);
  float s = fmaf(rf * y, ps, rf);
  float pc = fmaf(y, -2.7557319e-07f, 2.4801587e-05f);
  pc = fmaf(y, pc, -1.3888889e-03f);
  pc = fmaf(y, pc, 4.1666668e-02f);
  pc = fmaf(y, pc, -0.5f);
  float c = fmaf(y, pc, 1.0f);
  int q = ((int)kd) & 3;
  float rs = (q & 1) ? c : s;
  return (q & 2) ? -rs : rs;
}

__device__ __forceinline__ float apply_act(float v, int act) {
  switch (act) {
    case ACT_LRELU:    return v >= 0.0f ? v : 0.1f * v;
    case ACT_SOFTPLUS: return fmaxf(v, 0.0f) + log1pf(expf(-fabsf(v)));
    case ACT_SIGMOID:  return 1.0f / (1.0f + expf(-v));
  }
  return v;
}

// ---------------- conv kernels (accuracy-insensitive, f32) ----------------
__global__ void dw_conv3(const float* __restrict__ x, const float* __restrict__ w,
                         const float* __restrict__ bias, float* __restrict__ y, int Cc) {
  int t = blockIdx.x * blockDim.x + threadIdx.x;
  int c = blockIdx.y, b = blockIdx.z;
  if (t >= T_) return;
  const float* xb = x + ((size_t)b * Cc + c) * T_;
  float xm = (t > 0) ? xb[t - 1] : 0.0f;
  float x0 = xb[t];
  float xp = (t < T_ - 1) ? xb[t + 1] : 0.0f;
  const float* wc = w + (size_t)c * 3;
  float r = fmaf(xm, wc[0], fmaf(x0, wc[1], fmaf(xp, wc[2], bias[c])));
  y[((size_t)b * Cc + c) * T_ + t] = r;
}

__global__ void pw_conv(const float* __restrict__ x, const float* __restrict__ w,
                        const float* __restrict__ bias, float* __restrict__ y,
                        int Cin, int Cout, int act) {
  __shared__ float sx[256];
  int t = blockIdx.x, b = blockIdx.y, o = threadIdx.x;
  for (int i = o; i < Cin; i += blockDim.x) sx[i] = x[((size_t)b * Cin + i) * T_ + t];
  __syncthreads();
  if (o >= Cout) return;
  float acc = bias[o];
  const float* wo = w + (size_t)o * Cin;
  for (int cc = 0; cc < Cin; ++cc) acc = fmaf(wo[cc], sx[cc], acc);
  y[((size_t)b * Cout + o) * T_ + t] = apply_act(acc, act);
}

__global__ void conv3_full(const float* __restrict__ x, const float* __restrict__ w,
                           const float* __restrict__ bias, float* __restrict__ y,
                           int Cin, int Cout, int act) {
  __shared__ float sx[3 * 256];
  int t = blockIdx.x, b = blockIdx.y, o = threadIdx.x;
  for (int i = o; i < 3 * Cin; i += blockDim.x) {
    int k = i / Cin, cc = i - k * Cin;
    int tt = t + k - 1;
    sx[i] = (tt >= 0 && tt < T_) ? x[((size_t)b * Cin + cc) * T_ + tt] : 0.0f;
  }
  __syncthreads();
  if (o >= Cout) return;
  float acc = bias[o];
  for (int cc = 0; cc < Cin; ++cc) {
    const float* wo = w + ((size_t)o * Cin + cc) * 3;
    acc = fmaf(sx[cc], wo[0], acc);
    acc = fmaf(sx[Cin + cc], wo[1], acc);
    acc = fmaf(sx[2 * Cin + cc], wo[2], acc);
  }
  y[((size_t)b * Cout + o) * T_ + t] = apply_act(acc, act);
}

__global__ void pw_small(const float* __restrict__ x, const float* __restrict__ w,
                         const float* __restrict__ bias, float* __restrict__ y,
                         int Cin, int Cout, int act) {
  int idx = blockIdx.x * blockDim.x + threadIdx.x;
  int total = B_ * Cout * T_;
  if (idx >= total) return;
  int t = idx % T_;
  int o = (idx / T_) % Cout;
  int b = idx / (T_ * Cout);
  float acc = bias[o];
  const float* wo = w + (size_t)o * Cin;
  const float* xb = x + (size_t)b * Cin * T_ + t;
  for (int cc = 0; cc < Cin; ++cc) acc = fmaf(wo[cc], xb[(size_t)cc * T_], acc);
  y[((size_t)b * Cout + o) * T_ + t] = apply_act(acc, act);
}

__global__ void shaped_kernel(const float* __restrict__ ha, const float* __restrict__ fp,
                              const float* __restrict__ f0, float* __restrict__ out) {
  int t = blockIdx.x, b = blockIdx.y, h = threadIdx.x;
  __shared__ float ff[5], nm[5];
  if (h < 10) {
    float v = fp[((size_t)b * 10 + h) * T_ + t];
    if (h < 5) {
      ff[h] = 200.0f + 3300.0f * (1.0f / (1.0f + expf(-v)));
    } else {
      float bw = 50.0f + 150.0f * (fmaxf(v, 0.0f) + log1pf(expf(-fabsf(v))));
      nm[h - 5] = bw * bw;
    }
  }
  __syncthreads();
  if (h >= NH_) return;
  float hfreq = (float)(h + 1) * f0[(size_t)b * T_ + t];
  float g = 1.0f;
  for (int i = 0; i < 5; ++i) {
    float d = hfreq - ff[i];
    float den = d * d + nm[i];
    float res = nm[i] / fmaxf(den, 1e-5f);
    g = g * (0.8f + 0.2f * res);
  }
  out[((size_t)b * NH_ + h) * T_ + t] = ha[((size_t)b * NH_ + h) * T_ + t] * g;
}

// terms (f32, literal op order), layout [B][L]
__global__ void terms_kernel(const float* __restrict__ f0, float* __restrict__ terms) {
  int gid = blockIdx.x * blockDim.x + threadIdx.x;
  if (gid >= B_ * L_) return;
  int b = gid / L_;
  int l = gid - b * L_;
  const float RINV = (float)(500.0 / 120000.0);
  float pos = __fsub_rn(__fmul_rn(__fadd_rn((float)l, 0.5f), RINV), 0.5f);
  pos = fminf(fmaxf(pos, 0.0f), 499.0f);
  int lo = (int)floorf(pos);
  int hi = lo + 1; hi = hi < (T_ - 1) ? hi : (T_ - 1);
  float w = __fsub_rn(pos, (float)lo);
  float omw = __fsub_rn(1.0f, w);
  const float* f0b = f0 + (size_t)b * T_;
  float f0up = __fadd_rn(__fmul_rn(f0b[lo], omw), __fmul_rn(f0b[hi], w));
  terms[gid] = __fdiv_rn(__fmul_rn((float)6.283185307179586, f0up), 24000.0f);
}

// ---- XLA ReduceWindowRewriter(base=16) replication, 4 recursion levels, all f32 ----
// L1: inner sequential 16-scans of terms (7500 rows, exact)
__global__ void rwr_l1(const float* __restrict__ trm, float* __restrict__ A1) {
  int gid = blockIdx.x * blockDim.x + threadIdx.x;
  if (gid >= B_ * N1_) return;
  int b = gid / N1_, w = gid - b * N1_;
  const float* t = trm + (size_t)b * L_ + (size_t)w * 16;
  float* a = A1 + (size_t)b * L_ + (size_t)w * 16;
  float S = 0.0f;
  for (int i = 0; i < 16; ++i) { S = __fadd_rn(S, t[i]); a[i] = S; }
}
// L2: inner 16-scans of s1[i]=A1[i*16+15] (i<7500, pad 0), width 7504
__global__ void rwr_l2(const float* __restrict__ A1, float* __restrict__ A2) {
  int gid = blockIdx.x * blockDim.x + threadIdx.x;
  if (gid >= B_ * N2_) return;
  int b = gid / N2_, w = gid - b * N2_;
  float S = 0.0f;
  for (int m = 0; m < 16; ++m) {
    int i = w * 16 + m;
    float v = (i < N1_) ? A1[(size_t)b * L_ + (size_t)i * 16 + 15] : 0.0f;
    S = __fadd_rn(S, v);
    A2[(size_t)b * N2P_ + i] = S;
  }
}
// L3: inner 16-scans of s2[i]=A2[i*16+15] (i<469, pad 0), width 480
__global__ void rwr_l3(const float* __restrict__ A2, float* __restrict__ A3) {
  int gid = blockIdx.x * blockDim.x + threadIdx.x;
  if (gid >= B_ * N3_) return;
  int b = gid / N3_, w = gid - b * N3_;
  float S = 0.0f;
  for (int m = 0; m < 16; ++m) {
    int i = w * 16 + m;
    float v = (i < N2_) ? A2[(size_t)b * N2P_ + (size_t)i * 16 + 15] : 0.0f;
    S = __fadd_rn(S, v);
    A3[(size_t)b * N3P_ + i] = S;
  }
}
// L4: inner 16-scans of s3[i]=A3[i*16+15] (i<30, pad 0), width 32
__global__ void rwr_l4(const float* __restrict__ A3, float* __restrict__ A4) {
  int gid = blockIdx.x * blockDim.x + threadIdx.x;
  if (gid >= B_ * N4_) return;
  int b = gid / N4_, w = gid - b * N4_;
  float S = 0.0f;
  for (int m = 0; m < 16; ++m) {
    int i = w * 16 + m;
    float v = (i < N3_) ? A3[(size_t)b * N3P_ + (size_t)i * 16 + 15] : 0.0f;
    S = __fadd_rn(S, v);
    A4[(size_t)b * N4P_ + i] = S;
  }
}
// L5 terminal: exclusive seq scan of the 2 level-4 window sums
__global__ void rwr_l5(const float* __restrict__ A4, float* __restrict__ E5) {
  int b = threadIdx.x;
  if (b >= B_) return;
  E5[b * N4_ + 0] = 0.0f;
  E5[b * N4_ + 1] = A4[(size_t)b * N4P_ + 15];  // fl(0 + s4[0])
}
// EoffL3[k], k<30: 0 if k==0 else fl(E5[(k-1)>>4] + A4[k-1])
__global__ void rwr_e3(const float* __restrict__ A4, const float* __restrict__ E5,
                       float* __restrict__ E3o) {
  int gid = blockIdx.x * blockDim.x + threadIdx.x;
  if (gid >= B_ * N3_) return;
  int b = gid / N3_, k = gid - b * N3_;
  float v = 0.0f;
  if (k > 0) {
    int i = k - 1;
    v = __fadd_rn(E5[b * N4_ + (i >> 4)], A4[(size_t)b * N4P_ + i]);
  }
  E3o[b * N3_ + k] = v;
}
// EoffL2[j], j<469: 0 if j==0 else fl(E3o[(j-1)>>4] + A3[j-1])
__global__ void rwr_e2(const float* __restrict__ A3, const float* __restrict__ E3o,
                       float* __restrict__ E2o) {
  int gid = blockIdx.x * blockDim.x + threadIdx.x;
  if (gid >= B_ * N2_) return;
  int b = gid / N2_, j = gid - b * N2_;
  float v = 0.0f;
  if (j > 0) {
    int i = j - 1;
    v = __fadd_rn(E3o[b * N3_ + (i >> 4)], A3[(size_t)b * N3P_ + i]);
  }
  E2o[b * N2_ + j] = v;
}
// EoffL1[r], r<7500: 0 if r==0 else fl(E2o[(r-1)>>4] + A2[r-1])
__global__ void rwr_e1(const float* __restrict__ A2, const float* __restrict__ E2o,
                       float* __restrict__ E1o) {
  int gid = blockIdx.x * blockDim.x + threadIdx.x;
  if (gid >= B_ * N1_) return;
  int b = gid / N1_, r = gid - b * N1_;
  float v = 0.0f;
  if (r > 0) {
    int i = r - 1;
    v = __fadd_rn(E2o[b * N2_ + (i >> 4)], A2[(size_t)b * N2P_ + i]);
  }
  E1o[b * N1_ + r] = v;
}

// ---------------- main synthesis kernel (f32-literal; phi = fl(E1o + A1)) ----------------
__global__ void __launch_bounds__(256) main_kernel(
    const float* __restrict__ A1, const float* __restrict__ E1o,
    const float* __restrict__ shaped, const float* __restrict__ q,
    const float* __restrict__ f0, float* __restrict__ out,
    uint32_t k10, uint32_t k11, uint32_t k20, uint32_t k21, uint32_t k30, uint32_t k31) {
  const float RINV = (float)(500.0 / 120000.0);
  int b = blockIdx.y;
  int l0 = blockIdx.x * 256;
  int l = l0 + threadIdx.x;
  __shared__ float ls[4][NH_];
  float p0 = __fsub_rn(__fmul_rn(__fadd_rn((float)l0, 0.5f), RINV), 0.5f);
  p0 = fminf(fmaxf(p0, 0.0f), 499.0f);
  int lo0 = (int)floorf(p0);
  for (int i = threadIdx.x; i < 4 * NH_; i += 256) {
    int j = i / NH_, h = i - j * NH_;
    int col = lo0 + j; col = col < (T_ - 1) ? col : (T_ - 1);
    ls[j][h] = shaped[((size_t)b * NH_ + h) * T_ + col];
  }
  __syncthreads();
  if (l >= L_) return;

  float pos = __fsub_rn(__fmul_rn(__fadd_rn((float)l, 0.5f), RINV), 0.5f);
  pos = fminf(fmaxf(pos, 0.0f), 499.0f);
  int lo = (int)floorf(pos);
  int hi = lo + 1; hi = hi < (T_ - 1) ? hi : (T_ - 1);
  float w = __fsub_rn(pos, (float)lo);
  float omw = __fsub_rn(1.0f, w);

  const float* f0b = f0 + (size_t)b * T_;
  float f0up = __fadd_rn(__fmul_rn(f0b[lo], omw), __fmul_rn(f0b[hi], w));
  const float* qb = q + (size_t)b * 3 * T_;
  float q0 = __fadd_rn(__fmul_rn(qb[lo], omw), __fmul_rn(qb[hi], w));
  float q1 = __fadd_rn(__fmul_rn(qb[T_ + lo], omw), __fmul_rn(qb[T_ + hi], w));
  float q2 = __fadd_rn(__fmul_rn(qb[2 * T_ + lo], omw), __fmul_rn(qb[2 * T_ + hi], w));
  float jit = __fmul_rn(q0, 0.05f);
  float shm = __fmul_rn(q1, 0.15f);
  float brt = __fmul_rn(q2, 0.3f);

  uint32_t e = (uint32_t)(b * L_ + l);
  float n1 = jax_normal(k10, k11, e);
  float n2 = jax_normal(k20, k21, e);
  float n3 = jax_normal(k30, k31, e);

  // phase = RWR(16) four-level f32 scan: fl(E1o[window] + inner_prefix)
  float phf = __fadd_rn(E1o[b * N1_ + (l >> 4)], A1[(size_t)b * L_ + l]);
  float jph = __fadd_rn(phf, __fmul_rn(jit, n1));

  int jlo = lo - lo0;
  int jhi = hi - lo0; jhi = jhi < 3 ? jhi : 3;

  float acc = 0.0f;
  for (int h = 1; h <= NH_; ++h) {
    float amp = __fadd_rn(__fmul_rn(ls[jlo][h - 1], omw), __fmul_rn(ls[jhi][h - 1], w));
    float hf = (float)h;
    float arg = __fmul_rn(jph, hf);
    float s = sin_acc(arg);
    float m = (__fmul_rn(hf, f0up) < 12000.0f) ? 1.0f : 0.0f;
    acc = __fadd_rn(acc, __fmul_rn(__fmul_rn(amp, s), m));
  }
  float env = __fadd_rn(1.0f, __fmul_rn(n2, shm));
  out[(size_t)b * L_ + l] = __fadd_rn(__fmul_rn(acc, env), __fmul_rn(n3, brt));
}

extern "C" void kernel_launch(void* const* d_in, const int* in_sizes, int n_in,
                              void* d_out, int out_size, void* d_ws, size_t ws_size,
                              hipStream_t stream) {
  const float* f0    = (const float*)d_in[0];
  const float* cond  = (const float*)d_in[1];
  const float* ha_w1 = (const float*)d_in[2];
  const float* ha_b1 = (const float*)d_in[3];
  const float* ha_w2 = (const float*)d_in[4];
  const float* ha_b2 = (const float*)d_in[5];
  const float* ha_w3 = (const float*)d_in[6];
  const float* ha_b3 = (const float*)d_in[7];
  const float* ha_w4 = (const float*)d_in[8];
  const float* ha_b4 = (const float*)d_in[9];
  const float* ha_w5 = (const float*)d_in[10];
  const float* ha_b5 = (const float*)d_in[11];
  const float* fm_w1 = (const float*)d_in[12];
  const float* fm_b1 = (const float*)d_in[13];
  const float* fm_w2 = (const float*)d_in[14];
  const float* fm_b2 = (const float*)d_in[15];
  const float* fm_w3 = (const float*)d_in[16];
  const float* fm_b3 = (const float*)d_in[17];
  const float* vq_w1 = (const float*)d_in[18];
  const float* vq_b1 = (const float*)d_in[19];
  const float* vq_w2 = (const float*)d_in[20];
  const float* vq_b2 = (const float*)d_in[21];
  const float* vq_w3 = (const float*)d_in[22];
  const float* vq_b3 = (const float*)d_in[23];
  float* out = (float*)d_out;

  // split(key(42), 3), foldlike/partitionable
  uint32_t kw[3][2];
  for (uint32_t j = 0; j < 3; ++j) {
    uint32_t x0 = 0u, x1 = j;
    tf_block(0u, 42u, x0, x1);
    kw[j][0] = x0; kw[j][1] = x1;
  }

  // workspace layout (floats)
  float* ws = (float*)d_ws;
  size_t off = 0;
  auto take = [&](size_t n) { float* p = ws + off; off += (n + 3) & ~(size_t)3; return p; };
  float* Abuf = take(512000);
  float* Bb   = take(512000);
  float* C    = take(512000);
  float* ha   = take((size_t)B_ * NH_ * T_);
  float* fp   = take((size_t)B_ * 10 * T_);
  float* qv   = take((size_t)B_ * 3 * T_);
  float* sh   = take((size_t)B_ * NH_ * T_);
  float* trm  = take((size_t)B_ * L_);
  float* A1   = take((size_t)B_ * L_);
  float* A2   = take((size_t)B_ * N2P_);
  float* A3   = take((size_t)B_ * N3P_);
  float* A4   = take((size_t)B_ * N4P_);
  float* E5   = take((size_t)B_ * N4_);
  float* E3o  = take((size_t)B_ * N3_);
  float* E2o  = take((size_t)B_ * N2_);
  float* E1o  = take((size_t)B_ * N1_);

  // harmonic_amplitude_net
  dw_conv3<<<dim3((T_ + 127) / 128, 128, B_), 128, 0, stream>>>(cond, ha_w1, ha_b1, Abuf, 128);
  pw_conv<<<dim3(T_, B_), 256, 0, stream>>>(Abuf, ha_w2, ha_b2, Bb, 128, 256, ACT_LRELU);
  dw_conv3<<<dim3((T_ + 127) / 128, 256, B_), 128, 0, stream>>>(Bb, ha_w3, ha_b3, C, 256);
  pw_conv<<<dim3(T_, B_), 256, 0, stream>>>(C, ha_w4, ha_b4, Bb, 256, 256, ACT_LRELU);
  pw_conv<<<dim3(T_, B_), 128, 0, stream>>>(Bb, ha_w5, ha_b5, ha, 256, 100, ACT_SOFTPLUS);
  // formant net
  conv3_full<<<dim3(T_, B_), 256, 0, stream>>>(cond, fm_w1, fm_b1, Abuf, 128, 256, ACT_LRELU);
  conv3_full<<<dim3(T_, B_), 256, 0, stream>>>(Abuf, fm_w2, fm_b2, C, 256, 256, ACT_LRELU);
  pw_small<<<(B_ * 10 * T_ + 255) / 256, 256, 0, stream>>>(C, fm_w3, fm_b3, fp, 256, 10, ACT_NONE);
  // voice-quality net
  conv3_full<<<dim3(T_, B_), 128, 0, stream>>>(cond, vq_w1, vq_b1, Bb, 128, 128, ACT_LRELU);
  conv3_full<<<dim3(T_, B_), 64, 0, stream>>>(Bb, vq_w2, vq_b2, Abuf, 128, 64, ACT_LRELU);
  pw_small<<<(B_ * 3 * T_ + 255) / 256, 256, 0, stream>>>(Abuf, vq_w3, vq_b3, qv, 64, 3, ACT_SIGMOID);
  // shaped amplitudes
  shaped_kernel<<<dim3(T_, B_), 128, 0, stream>>>(ha, fp, f0, sh);
  // f32 terms -> ReduceWindowRewriter(16) scan, all f32
  terms_kernel<<<(B_ * L_ + 255) / 256, 256, 0, stream>>>(f0, trm);
  rwr_l1<<<(B_ * N1_ + 255) / 256, 256, 0, stream>>>(trm, A1);
  rwr_l2<<<(B_ * N2_ + 255) / 256, 256, 0, stream>>>(A1, A2);
  rwr_l3<<<1, 128, 0, stream>>>(A2, A3);
  rwr_l4<<<1, 64, 0, stream>>>(A3, A4);
  rwr_l5<<<1, 64, 0, stream>>>(A4, E5);
  rwr_e3<<<1, 128, 0, stream>>>(A4, E5, E3o);
  rwr_e2<<<(B_ * N2_ + 255) / 256, 256, 0, stream>>>(A3, E3o, E2o);
  rwr_e1<<<(B_ * N1_ + 255) / 256, 256, 0, stream>>>(A2, E2o, E1o);
  // synthesis
  main_kernel<<<dim3((L_ + 255) / 256, B_), 256, 0, stream>>>(
      A1, E1o, sh, qv, f0, out,
      kw[0][0], kw[0][1], kw[1][0], kw[1][1], kw[2][0], kw[2][1]);
  (void)in_sizes; (void)n_in; (void)out_size; (void)ws_size;
}

// Round 10
// 532.795 us; speedup vs baseline: 1.4728x; 1.4728x over previous
//
#include <hip/hip_runtime.h>
#include <stdint.h>

#define B_ 4
#define T_ 500
#define L_ 120000
#define NH_ 100
// RWR(16) level sizes (verified R9 — DO NOT TOUCH)
#define N1_ 7500
#define N2_ 469
#define N2P_ 7504
#define N3_ 30
#define N3P_ 480
#define N4_ 2
#define N4P_ 32

#define ACT_NONE 0
#define ACT_LRELU 1
#define ACT_SOFTPLUS 2
#define ACT_SIGMOID 3

#define CCT 128  // cc chunk for conv tiling

// ---------------- Threefry2x32-20 (verified R9) ----------------
__host__ __device__ __forceinline__ uint32_t tf_rotl(uint32_t v, int d) {
  return (v << d) | (v >> (32 - d));
}
__host__ __device__ __forceinline__ void tf_block(uint32_t k0, uint32_t k1,
                                                  uint32_t& x0, uint32_t& x1) {
  uint32_t k2 = k0 ^ k1 ^ 0x1BD11BDAu;
  x0 += k0; x1 += k1;
#define TF_R(d) x0 += x1; x1 = tf_rotl(x1, (d)); x1 ^= x0;
  TF_R(13) TF_R(15) TF_R(26) TF_R(6)   x0 += k1; x1 += k2 + 1u;
  TF_R(17) TF_R(29) TF_R(16) TF_R(24)  x0 += k2; x1 += k0 + 2u;
  TF_R(13) TF_R(15) TF_R(26) TF_R(6)   x0 += k0; x1 += k1 + 3u;
  TF_R(17) TF_R(29) TF_R(16) TF_R(24)  x0 += k1; x1 += k2 + 4u;
  TF_R(13) TF_R(15) TF_R(26) TF_R(6)   x0 += k2; x1 += k0 + 5u;
#undef TF_R
}

__device__ __forceinline__ float erfinv_xla(float x) {
  float w = -log1pf(-(x * x));
  float p;
  if (w < 5.0f) {
    w = w - 2.5f;
    p = 2.81022636e-08f;
    p = fmaf(p, w, 3.43273939e-07f);
    p = fmaf(p, w, -3.5233877e-06f);
    p = fmaf(p, w, -4.39150654e-06f);
    p = fmaf(p, w, 0.00021858087f);
    p = fmaf(p, w, -0.00125372503f);
    p = fmaf(p, w, -0.00417768164f);
    p = fmaf(p, w, 0.246640727f);
    p = fmaf(p, w, 1.50140941f);
  } else {
    w = sqrtf(w) - 3.0f;
    p = -0.000200214257f;
    p = fmaf(p, w, 0.000100950558f);
    p = fmaf(p, w, 0.00134934322f);
    p = fmaf(p, w, -0.00367342844f);
    p = fmaf(p, w, 0.00573950773f);
    p = fmaf(p, w, -0.0076224613f);
    p = fmaf(p, w, 0.00943887047f);
    p = fmaf(p, w, 1.00167406f);
    p = fmaf(p, w, 2.83297682f);
  }
  return p * x;
}

__device__ __forceinline__ float jax_normal(uint32_t k0, uint32_t k1, uint32_t e) {
  uint32_t x0 = 0u, x1 = e;
  tf_block(k0, k1, x0, x1);
  uint32_t bits = x0 ^ x1;
  float u = __uint_as_float((bits >> 9) | 0x3f800000u) - 1.0f;
  float v = __fadd_rn(__fmul_rn(u, 2.0f), -0x1.fffffep-1f);
  v = fmaxf(v, -0x1.fffffep-1f);
  return __fmul_rn((float)1.4142135623730951, erfinv_xla(v));
}

// accurate sin of an EXACT f32 argument: f64 Cody-Waite reduction (verified R9)
__device__ __forceinline__ float sin_acc(float xf) {
  double x = (double)xf;
  double kd = rint(x * 6.3661977236758138e-01);
  double r = fma(-kd, 1.5707963267948966e+00, x);
  r = fma(-kd, 6.1232339957367660e-17, r);
  float rf = (float)r;
  float y = rf * rf;
  float ps = fmaf(y, 2.7557319e-06f, -1.9841270e-04f);
  ps = fmaf(y, ps, 8.3333335e-03f);
  ps = fmaf(y, ps, -0.16666667f);
  float s = fmaf(rf * y, ps, rf);
  float pc = fmaf(y, -2.7557319e-07f, 2.4801587e-05f);
  pc = fmaf(y, pc, -1.3888889e-03f);
  pc = fmaf(y, pc, 4.1666668e-02f);
  pc = fmaf(y, pc, -0.5f);
  float c = fmaf(y, pc, 1.0f);
  int q = ((int)kd) & 3;
  float rs = (q & 1) ? c : s;
  return (q & 2) ? -rs : rs;
}

__device__ __forceinline__ float apply_act(float v, int act) {
  switch (act) {
    case ACT_LRELU:    return v >= 0.0f ? v : 0.1f * v;
    case ACT_SOFTPLUS: return fmaxf(v, 0.0f) + log1pf(expf(-fabsf(v)));
    case ACT_SIGMOID:  return 1.0f / (1.0f + expf(-v));
  }
  return v;
}

// ---------------- conv kernels ----------------
__global__ void dw_conv3(const float* __restrict__ x, const float* __restrict__ w,
                         const float* __restrict__ bias, float* __restrict__ y, int Cc) {
  int t = blockIdx.x * blockDim.x + threadIdx.x;
  int c = blockIdx.y, b = blockIdx.z;
  if (t >= T_) return;
  const float* xb = x + ((size_t)b * Cc + c) * T_;
  float xm = (t > 0) ? xb[t - 1] : 0.0f;
  float x0 = xb[t];
  float xp = (t < T_ - 1) ? xb[t + 1] : 0.0f;
  const float* wc = w + (size_t)c * 3;
  float r = fmaf(xm, wc[0], fmaf(x0, wc[1], fmaf(xp, wc[2], bias[c])));
  y[((size_t)b * Cc + c) * T_ + t] = r;
}

// Tiled K=3 conv: block = 64 t-lanes x 4 o-groups, thread computes 4 outputs.
// Weight address is wave-uniform (one cache line per load, broadcast).
// FMA chain order per output matches the original conv3_full exactly -> bitwise identical.
__global__ void __launch_bounds__(256) conv3_tiled(
    const float* __restrict__ x, const float* __restrict__ w,
    const float* __restrict__ bias, float* __restrict__ y,
    int Cin, int Cout, int act) {
  __shared__ float sx[CCT][66];
  int t0 = blockIdx.x * 64;
  int o0 = blockIdx.y * 16;
  int b = blockIdx.z;
  int lane = threadIdx.x & 63;
  int og = threadIdx.x >> 6;
  int t = t0 + lane;
  int o[4];
  float acc[4];
#pragma unroll
  for (int i = 0; i < 4; ++i) {
    o[i] = o0 + og + 4 * i;
    acc[i] = (o[i] < Cout) ? bias[o[i]] : 0.0f;
  }
  for (int c0 = 0; c0 < Cin; c0 += CCT) {
    __syncthreads();
    for (int idx = threadIdx.x; idx < CCT * 66; idx += 256) {
      int cc = idx / 66, j = idx - cc * 66;
      int tt = t0 - 1 + j;
      sx[cc][j] = (tt >= 0 && tt < T_) ? x[((size_t)b * Cin + c0 + cc) * T_ + tt] : 0.0f;
    }
    __syncthreads();
    for (int cc = 0; cc < CCT; ++cc) {
      float xm = sx[cc][lane];
      float x0v = sx[cc][lane + 1];
      float xp = sx[cc][lane + 2];
#pragma unroll
      for (int i = 0; i < 4; ++i) {
        const float* wo = w + ((size_t)o[i] * Cin + c0 + cc) * 3;
        acc[i] = fmaf(xm, wo[0], acc[i]);
        acc[i] = fmaf(x0v, wo[1], acc[i]);
        acc[i] = fmaf(xp, wo[2], acc[i]);
      }
    }
  }
  if (t < T_) {
#pragma unroll
    for (int i = 0; i < 4; ++i)
      if (o[i] < Cout) y[((size_t)b * Cout + o[i]) * T_ + t] = apply_act(acc[i], act);
  }
}

// Tiled K=1 pointwise conv, same layout. cc ascending, acc=bias start -> bitwise identical.
__global__ void __launch_bounds__(256) pw_tiled(
    const float* __restrict__ x, const float* __restrict__ w,
    const float* __restrict__ bias, float* __restrict__ y,
    int Cin, int Cout, int act) {
  __shared__ float sx[CCT][64];
  int t0 = blockIdx.x * 64;
  int o0 = blockIdx.y * 16;
  int b = blockIdx.z;
  int lane = threadIdx.x & 63;
  int og = threadIdx.x >> 6;
  int t = t0 + lane;
  int o[4];
  float acc[4];
#pragma unroll
  for (int i = 0; i < 4; ++i) {
    o[i] = o0 + og + 4 * i;
    acc[i] = (o[i] < Cout) ? bias[o[i]] : 0.0f;
  }
  for (int c0 = 0; c0 < Cin; c0 += CCT) {
    __syncthreads();
    for (int idx = threadIdx.x; idx < CCT * 64; idx += 256) {
      int cc = idx >> 6, j = idx & 63;
      int tt = t0 + j;
      sx[cc][j] = (tt < T_) ? x[((size_t)b * Cin + c0 + cc) * T_ + tt] : 0.0f;
    }
    __syncthreads();
    for (int cc = 0; cc < CCT; ++cc) {
      float xv = sx[cc][lane];
#pragma unroll
      for (int i = 0; i < 4; ++i)
        acc[i] = fmaf(xv, w[(size_t)o[i] * Cin + c0 + cc], acc[i]);
    }
  }
  if (t < T_) {
#pragma unroll
    for (int i = 0; i < 4; ++i)
      if (o[i] < Cout) y[((size_t)b * Cout + o[i]) * T_ + t] = apply_act(acc[i], act);
  }
}

__global__ void pw_small(const float* __restrict__ x, const float* __restrict__ w,
                         const float* __restrict__ bias, float* __restrict__ y,
                         int Cin, int Cout, int act) {
  int idx = blockIdx.x * blockDim.x + threadIdx.x;
  int total = B_ * Cout * T_;
  if (idx >= total) return;
  int t = idx % T_;
  int o = (idx / T_) % Cout;
  int b = idx / (T_ * Cout);
  float acc = bias[o];
  const float* wo = w + (size_t)o * Cin;
  const float* xb = x + (size_t)b * Cin * T_ + t;
  for (int cc = 0; cc < Cin; ++cc) acc = fmaf(wo[cc], xb[(size_t)cc * T_], acc);
  y[((size_t)b * Cout + o) * T_ + t] = apply_act(acc, act);
}

__global__ void shaped_kernel(const float* __restrict__ ha, const float* __restrict__ fp,
                              const float* __restrict__ f0, float* __restrict__ out) {
  int t = blockIdx.x, b = blockIdx.y, h = threadIdx.x;
  __shared__ float ff[5], nm[5];
  if (h < 10) {
    float v = fp[((size_t)b * 10 + h) * T_ + t];
    if (h < 5) {
      ff[h] = 200.0f + 3300.0f * (1.0f / (1.0f + expf(-v)));
    } else {
      float bw = 50.0f + 150.0f * (fmaxf(v, 0.0f) + log1pf(expf(-fabsf(v))));
      nm[h - 5] = bw * bw;
    }
  }
  __syncthreads();
  if (h >= NH_) return;
  float hfreq = (float)(h + 1) * f0[(size_t)b * T_ + t];
  float g = 1.0f;
  for (int i = 0; i < 5; ++i) {
    float d = hfreq - ff[i];
    float den = d * d + nm[i];
    float res = nm[i] / fmaxf(den, 1e-5f);
    g = g * (0.8f + 0.2f * res);
  }
  out[((size_t)b * NH_ + h) * T_ + t] = ha[((size_t)b * NH_ + h) * T_ + t] * g;
}

// terms (f32, literal op order), layout [B][L] (verified R9)
__global__ void terms_kernel(const float* __restrict__ f0, float* __restrict__ terms) {
  int gid = blockIdx.x * blockDim.x + threadIdx.x;
  if (gid >= B_ * L_) return;
  int b = gid / L_;
  int l = gid - b * L_;
  const float RINV = (float)(500.0 / 120000.0);
  float pos = __fsub_rn(__fmul_rn(__fadd_rn((float)l, 0.5f), RINV), 0.5f);
  pos = fminf(fmaxf(pos, 0.0f), 499.0f);
  int lo = (int)floorf(pos);
  int hi = lo + 1; hi = hi < (T_ - 1) ? hi : (T_ - 1);
  float w = __fsub_rn(pos, (float)lo);
  float omw = __fsub_rn(1.0f, w);
  const float* f0b = f0 + (size_t)b * T_;
  float f0up = __fadd_rn(__fmul_rn(f0b[lo], omw), __fmul_rn(f0b[hi], w));
  terms[gid] = __fdiv_rn(__fmul_rn((float)6.283185307179586, f0up), 24000.0f);
}

// ---- XLA ReduceWindowRewriter(base=16), 4 levels, all f32 (verified R9 — DO NOT TOUCH) ----
__global__ void rwr_l1(const float* __restrict__ trm, float* __restrict__ A1) {
  int gid = blockIdx.x * blockDim.x + threadIdx.x;
  if (gid >= B_ * N1_) return;
  int b = gid / N1_, w = gid - b * N1_;
  const float* t = trm + (size_t)b * L_ + (size_t)w * 16;
  float* a = A1 + (size_t)b * L_ + (size_t)w * 16;
  float S = 0.0f;
  for (int i = 0; i < 16; ++i) { S = __fadd_rn(S, t[i]); a[i] = S; }
}
__global__ void rwr_l2(const float* __restrict__ A1, float* __restrict__ A2) {
  int gid = blockIdx.x * blockDim.x + threadIdx.x;
  if (gid >= B_ * N2_) return;
  int b = gid / N2_, w = gid - b * N2_;
  float S = 0.0f;
  for (int m = 0; m < 16; ++m) {
    int i = w * 16 + m;
    float v = (i < N1_) ? A1[(size_t)b * L_ + (size_t)i * 16 + 15] : 0.0f;
    S = __fadd_rn(S, v);
    A2[(size_t)b * N2P_ + i] = S;
  }
}
__global__ void rwr_l3(const float* __restrict__ A2, float* __restrict__ A3) {
  int gid = blockIdx.x * blockDim.x + threadIdx.x;
  if (gid >= B_ * N3_) return;
  int b = gid / N3_, w = gid - b * N3_;
  float S = 0.0f;
  for (int m = 0; m < 16; ++m) {
    int i = w * 16 + m;
    float v = (i < N2_) ? A2[(size_t)b * N2P_ + (size_t)i * 16 + 15] : 0.0f;
    S = __fadd_rn(S, v);
    A3[(size_t)b * N3P_ + i] = S;
  }
}
__global__ void rwr_l4(const float* __restrict__ A3, float* __restrict__ A4) {
  int gid = blockIdx.x * blockDim.x + threadIdx.x;
  if (gid >= B_ * N4_) return;
  int b = gid / N4_, w = gid - b * N4_;
  float S = 0.0f;
  for (int m = 0; m < 16; ++m) {
    int i = w * 16 + m;
    float v = (i < N3_) ? A3[(size_t)b * N3P_ + (size_t)i * 16 + 15] : 0.0f;
    S = __fadd_rn(S, v);
    A4[(size_t)b * N4P_ + i] = S;
  }
}
__global__ void rwr_l5(const float* __restrict__ A4, float* __restrict__ E5) {
  int b = threadIdx.x;
  if (b >= B_) return;
  E5[b * N4_ + 0] = 0.0f;
  E5[b * N4_ + 1] = A4[(size_t)b * N4P_ + 15];
}
__global__ void rwr_e3(const float* __restrict__ A4, const float* __restrict__ E5,
                       float* __restrict__ E3o) {
  int gid = blockIdx.x * blockDim.x + threadIdx.x;
  if (gid >= B_ * N3_) return;
  int b = gid / N3_, k = gid - b * N3_;
  float v = 0.0f;
  if (k > 0) {
    int i = k - 1;
    v = __fadd_rn(E5[b * N4_ + (i >> 4)], A4[(size_t)b * N4P_ + i]);
  }
  E3o[b * N3_ + k] = v;
}
__global__ void rwr_e2(const float* __restrict__ A3, const float* __restrict__ E3o,
                       float* __restrict__ E2o) {
  int gid = blockIdx.x * blockDim.x + threadIdx.x;
  if (gid >= B_ * N2_) return;
  int b = gid / N2_, j = gid - b * N2_;
  float v = 0.0f;
  if (j > 0) {
    int i = j - 1;
    v = __fadd_rn(E3o[b * N3_ + (i >> 4)], A3[(size_t)b * N3P_ + i]);
  }
  E2o[b * N2_ + j] = v;
}
__global__ void rwr_e1(const float* __restrict__ A2, const float* __restrict__ E2o,
                       float* __restrict__ E1o) {
  int gid = blockIdx.x * blockDim.x + threadIdx.x;
  if (gid >= B_ * N1_) return;
  int b = gid / N1_, r = gid - b * N1_;
  float v = 0.0f;
  if (r > 0) {
    int i = r - 1;
    v = __fadd_rn(E2o[b * N2_ + (i >> 4)], A2[(size_t)b * N2P_ + i]);
  }
  E1o[b * N1_ + r] = v;
}

// ---------------- main synthesis kernel (verified R9 — numerics unchanged) ----------------
__global__ void __launch_bounds__(256) main_kernel(
    const float* __restrict__ A1, const float* __restrict__ E1o,
    const float* __restrict__ shaped, const float* __restrict__ q,
    const float* __restrict__ f0, float* __restrict__ out,
    uint32_t k10, uint32_t k11, uint32_t k20, uint32_t k21, uint32_t k30, uint32_t k31) {
  const float RINV = (float)(500.0 / 120000.0);
  int b = blockIdx.y;
  int l0 = blockIdx.x * 256;
  int l = l0 + threadIdx.x;
  __shared__ float ls[4][NH_];
  float p0 = __fsub_rn(__fmul_rn(__fadd_rn((float)l0, 0.5f), RINV), 0.5f);
  p0 = fminf(fmaxf(p0, 0.0f), 499.0f);
  int lo0 = (int)floorf(p0);
  for (int i = threadIdx.x; i < 4 * NH_; i += 256) {
    int j = i / NH_, h = i - j * NH_;
    int col = lo0 + j; col = col < (T_ - 1) ? col : (T_ - 1);
    ls[j][h] = shaped[((size_t)b * NH_ + h) * T_ + col];
  }
  __syncthreads();
  if (l >= L_) return;

  float pos = __fsub_rn(__fmul_rn(__fadd_rn((float)l, 0.5f), RINV), 0.5f);
  pos = fminf(fmaxf(pos, 0.0f), 499.0f);
  int lo = (int)floorf(pos);
  int hi = lo + 1; hi = hi < (T_ - 1) ? hi : (T_ - 1);
  float w = __fsub_rn(pos, (float)lo);
  float omw = __fsub_rn(1.0f, w);

  const float* f0b = f0 + (size_t)b * T_;
  float f0up = __fadd_rn(__fmul_rn(f0b[lo], omw), __fmul_rn(f0b[hi], w));
  const float* qb = q + (size_t)b * 3 * T_;
  float q0 = __fadd_rn(__fmul_rn(qb[lo], omw), __fmul_rn(qb[hi], w));
  float q1 = __fadd_rn(__fmul_rn(qb[T_ + lo], omw), __fmul_rn(qb[T_ + hi], w));
  float q2 = __fadd_rn(__fmul_rn(qb[2 * T_ + lo], omw), __fmul_rn(qb[2 * T_ + hi], w));
  float jit = __fmul_rn(q0, 0.05f);
  float shm = __fmul_rn(q1, 0.15f);
  float brt = __fmul_rn(q2, 0.3f);

  uint32_t e = (uint32_t)(b * L_ + l);
  float n1 = jax_normal(k10, k11, e);
  float n2 = jax_normal(k20, k21, e);
  float n3 = jax_normal(k30, k31, e);

  float phf = __fadd_rn(E1o[b * N1_ + (l >> 4)], A1[(size_t)b * L_ + l]);
  float jph = __fadd_rn(phf, __fmul_rn(jit, n1));

  int jlo = lo - lo0;
  int jhi = hi - lo0; jhi = jhi < 3 ? jhi : 3;

  float acc = 0.0f;
  for (int h = 1; h <= NH_; ++h) {
    float amp = __fadd_rn(__fmul_rn(ls[jlo][h - 1], omw), __fmul_rn(ls[jhi][h - 1], w));
    float hf = (float)h;
    float arg = __fmul_rn(jph, hf);
    float s = sin_acc(arg);
    float m = (__fmul_rn(hf, f0up) < 12000.0f) ? 1.0f : 0.0f;
    acc = __fadd_rn(acc, __fmul_rn(__fmul_rn(amp, s), m));
  }
  float env = __fadd_rn(1.0f, __fmul_rn(n2, shm));
  out[(size_t)b * L_ + l] = __fadd_rn(__fmul_rn(acc, env), __fmul_rn(n3, brt));
}

extern "C" void kernel_launch(void* const* d_in, const int* in_sizes, int n_in,
                              void* d_out, int out_size, void* d_ws, size_t ws_size,
                              hipStream_t stream) {
  const float* f0    = (const float*)d_in[0];
  const float* cond  = (const float*)d_in[1];
  const float* ha_w1 = (const float*)d_in[2];
  const float* ha_b1 = (const float*)d_in[3];
  const float* ha_w2 = (const float*)d_in[4];
  const float* ha_b2 = (const float*)d_in[5];
  const float* ha_w3 = (const float*)d_in[6];
  const float* ha_b3 = (const float*)d_in[7];
  const float* ha_w4 = (const float*)d_in[8];
  const float* ha_b4 = (const float*)d_in[9];
  const float* ha_w5 = (const float*)d_in[10];
  const float* ha_b5 = (const float*)d_in[11];
  const float* fm_w1 = (const float*)d_in[12];
  const float* fm_b1 = (const float*)d_in[13];
  const float* fm_w2 = (const float*)d_in[14];
  const float* fm_b2 = (const float*)d_in[15];
  const float* fm_w3 = (const float*)d_in[16];
  const float* fm_b3 = (const float*)d_in[17];
  const float* vq_w1 = (const float*)d_in[18];
  const float* vq_b1 = (const float*)d_in[19];
  const float* vq_w2 = (const float*)d_in[20];
  const float* vq_b2 = (const float*)d_in[21];
  const float* vq_w3 = (const float*)d_in[22];
  const float* vq_b3 = (const float*)d_in[23];
  float* out = (float*)d_out;

  // split(key(42), 3), foldlike/partitionable (verified)
  uint32_t kw[3][2];
  for (uint32_t j = 0; j < 3; ++j) {
    uint32_t x0 = 0u, x1 = j;
    tf_block(0u, 42u, x0, x1);
    kw[j][0] = x0; kw[j][1] = x1;
  }

  // workspace layout (floats)
  float* ws = (float*)d_ws;
  size_t off = 0;
  auto take = [&](size_t n) { float* p = ws + off; off += (n + 3) & ~(size_t)3; return p; };
  float* Abuf = take(512000);
  float* Bb   = take(512000);
  float* C    = take(512000);
  float* ha   = take((size_t)B_ * NH_ * T_);
  float* fp   = take((size_t)B_ * 10 * T_);
  float* qv   = take((size_t)B_ * 3 * T_);
  float* sh   = take((size_t)B_ * NH_ * T_);
  float* trm  = take((size_t)B_ * L_);
  float* A1   = take((size_t)B_ * L_);
  float* A2   = take((size_t)B_ * N2P_);
  float* A3   = take((size_t)B_ * N3P_);
  float* A4   = take((size_t)B_ * N4P_);
  float* E5   = take((size_t)B_ * N4_);
  float* E3o  = take((size_t)B_ * N3_);
  float* E2o  = take((size_t)B_ * N2_);
  float* E1o  = take((size_t)B_ * N1_);

  // phase chain first (independent of conv nets) — lets it overlap conv work
  terms_kernel<<<(B_ * L_ + 255) / 256, 256, 0, stream>>>(f0, trm);
  rwr_l1<<<(B_ * N1_ + 255) / 256, 256, 0, stream>>>(trm, A1);
  rwr_l2<<<(B_ * N2_ + 255) / 256, 256, 0, stream>>>(A1, A2);
  rwr_l3<<<1, 128, 0, stream>>>(A2, A3);
  rwr_l4<<<1, 64, 0, stream>>>(A3, A4);
  rwr_l5<<<1, 64, 0, stream>>>(A4, E5);
  rwr_e3<<<1, 128, 0, stream>>>(A4, E5, E3o);
  rwr_e2<<<(B_ * N2_ + 255) / 256, 256, 0, stream>>>(A3, E3o, E2o);
  rwr_e1<<<(B_ * N1_ + 255) / 256, 256, 0, stream>>>(A2, E2o, E1o);

  // harmonic_amplitude_net
  dw_conv3<<<dim3((T_ + 127) / 128, 128, B_), 128, 0, stream>>>(cond, ha_w1, ha_b1, Abuf, 128);
  pw_tiled<<<dim3(8, 16, B_), 256, 0, stream>>>(Abuf, ha_w2, ha_b2, Bb, 128, 256, ACT_LRELU);
  dw_conv3<<<dim3((T_ + 127) / 128, 256, B_), 128, 0, stream>>>(Bb, ha_w3, ha_b3, C, 256);
  pw_tiled<<<dim3(8, 16, B_), 256, 0, stream>>>(C, ha_w4, ha_b4, Bb, 256, 256, ACT_LRELU);
  pw_tiled<<<dim3(8, 7, B_), 256, 0, stream>>>(Bb, ha_w5, ha_b5, ha, 256, 100, ACT_SOFTPLUS);
  // formant net
  conv3_tiled<<<dim3(8, 16, B_), 256, 0, stream>>>(cond, fm_w1, fm_b1, Abuf, 128, 256, ACT_LRELU);
  conv3_tiled<<<dim3(8, 16, B_), 256, 0, stream>>>(Abuf, fm_w2, fm_b2, C, 256, 256, ACT_LRELU);
  pw_small<<<(B_ * 10 * T_ + 255) / 256, 256, 0, stream>>>(C, fm_w3, fm_b3, fp, 256, 10, ACT_NONE);
  // voice-quality net
  conv3_tiled<<<dim3(8, 8, B_), 256, 0, stream>>>(cond, vq_w1, vq_b1, Bb, 128, 128, ACT_LRELU);
  conv3_tiled<<<dim3(8, 4, B_), 256, 0, stream>>>(Bb, vq_w2, vq_b2, Abuf, 128, 64, ACT_LRELU);
  pw_small<<<(B_ * 3 * T_ + 255) / 256, 256, 0, stream>>>(Abuf, vq_w3, vq_b3, qv, 64, 3, ACT_SIGMOID);
  // shaped amplitudes
  shaped_kernel<<<dim3(T_, B_), 128, 0, stream>>>(ha, fp, f0, sh);
  // synthesis
  main_kernel<<<dim3((L_ + 255) / 256, B_), 256, 0, stream>>>(
      A1, E1o, sh, qv, f0, out,
      kw[0][0], kw[0][1], kw[1][0], kw[1][1], kw[2][0], kw[2][1]);
  (void)in_sizes; (void)n_in; (void)out_size; (void)ws_size;
}